// Round 1
// baseline (371.124 us; speedup 1.0000x reference)
//
#include <hip/hip_runtime.h>
#include <math.h>

#define NN 100000
#define NB 256        // coarse buckets
#define RANGE 392     // nodes per bucket (256*392 = 100352 >= 100000)
#define CAP 56        // staging entries per bucket per block
#define BCAP 13824    // bucket capacity (mean 12544, sigma ~112 -> 11 sigma)
#define NBLK_PART 512

typedef unsigned int uint;
typedef __attribute__((ext_vector_type(8))) short short8;
typedef __attribute__((ext_vector_type(4))) float f32x4;

// ---------------- partition: edges -> 256 dst-range buckets ----------------

__global__ __launch_bounds__(256) void partition_kernel(const int* __restrict__ src,
                                                        const int* __restrict__ dst,
                                                        int* __restrict__ bcur,
                                                        unsigned* __restrict__ bkt, int E) {
    __shared__ unsigned stage[NB * CAP];
    __shared__ int lcnt[NB];
    __shared__ int baseS[NB];
    for (int i = threadIdx.x; i < NB; i += 256) lcnt[i] = 0;
    __syncthreads();

    const int nq = E >> 2;
    const int stride = gridDim.x * blockDim.x;
    for (int q = blockIdx.x * blockDim.x + threadIdx.x; q < nq; q += stride) {
        const int4 s4 = ((const int4*)src)[q];
        const int4 d4 = ((const int4*)dst)[q];
#pragma unroll
        for (int k = 0; k < 4; k++) {
            const int s = (&s4.x)[k];
            const int d = (&d4.x)[k];
            const unsigned b = (unsigned)d / RANGE;
            const unsigned ent = ((unsigned)s << 9) | ((unsigned)d - b * RANGE);
            const int slot = atomicAdd(&lcnt[b], 1);
            if (slot < CAP) {
                stage[b * CAP + slot] = ent;
            } else {                       // rare overflow: direct global path
                const int pos = atomicAdd(&bcur[b], 1);
                if (pos < BCAP) bkt[(size_t)b * BCAP + pos] = ent;
            }
        }
    }
    // tail edges (E % 4)
    const int gid = blockIdx.x * blockDim.x + threadIdx.x;
    if (gid < (E & 3)) {
        const int e = (E & ~3) + gid;
        const int s = src[e], d = dst[e];
        const unsigned b = (unsigned)d / RANGE;
        const unsigned ent = ((unsigned)s << 9) | ((unsigned)d - b * RANGE);
        const int pos = atomicAdd(&bcur[b], 1);
        if (pos < BCAP) bkt[(size_t)b * BCAP + pos] = ent;
    }
    __syncthreads();

    // reserve all bucket bases in parallel (one atomic per bucket)
    if (threadIdx.x < NB) {
        const int c = min(lcnt[threadIdx.x], CAP);
        baseS[threadIdx.x] = (c > 0) ? atomicAdd(&bcur[threadIdx.x], c) : 0;
    }
    __syncthreads();

    // flush: contiguous chunk write per bucket
    const int w = threadIdx.x >> 6, l = threadIdx.x & 63;
    for (int b = w; b < NB; b += 4) {
        const int cnt = min(lcnt[b], CAP);
        const int base = baseS[b];
        for (int i = l; i < cnt; i += 64) {
            const int pos = base + i;
            if (pos < BCAP) bkt[(size_t)b * BCAP + pos] = stage[b * CAP + i];
        }
    }
}

// ---------------- per-bucket counting sort -> CSR (+deg/dinv) ----------------

__global__ __launch_bounds__(256) void bucket_sort_kernel(const int* __restrict__ bcur,
                                                          unsigned* __restrict__ bkt,
                                                          int* __restrict__ row_off,
                                                          int* __restrict__ deg,
                                                          float* __restrict__ dinv, int n) {
    __shared__ int sortedS[BCAP];
    __shared__ int cntS[RANGE];
    __shared__ int offS[RANGE];
    const int b = blockIdx.x;
    const int tid = threadIdx.x;
    unsigned* eb = bkt + (size_t)b * BCAP;
    const int m = min(bcur[b], BCAP);

    for (int i = tid; i < RANGE; i += 256) cntS[i] = 0;
    __syncthreads();
    for (int i = tid; i < m; i += 256) atomicAdd(&cntS[(int)(eb[i] & 511u)], 1);
    __syncthreads();

    // exclusive scan of cntS[0..RANGE) by wave 0
    if (tid < 64) {
        const int l = tid;
        int carry = 0;
        for (int base = 0; base < RANGE; base += 64) {
            const int i = base + l;
            const int c = (i < RANGE) ? cntS[i] : 0;
            int v = c;
#pragma unroll
            for (int off = 1; off < 64; off <<= 1) {
                const int t2 = __shfl_up(v, off);
                if (l >= off) v += t2;
            }
            if (i < RANGE) offS[i] = carry + v - c;
            carry += __shfl(v, 63);
        }
    }
    __syncthreads();

    // emit CSR metadata
    for (int i = tid; i < RANGE; i += 256) {
        const int node = b * RANGE + i;
        if (node < n) {
            row_off[node] = b * BCAP + offS[i];
            deg[node] = cntS[i];
            dinv[node] = rsqrtf((float)cntS[i] + 1.0f);   // +1 self-loop
        }
    }
    __syncthreads();

    // scatter into LDS (offS doubles as cursor now)
    for (int i = tid; i < m; i += 256) {
        const unsigned e = eb[i];
        const int pos = atomicAdd(&offS[(int)(e & 511u)], 1);
        sortedS[pos] = (int)(e >> 9);
    }
    __syncthreads();

    // in-place contiguous write-back (bkt segment becomes the nbr segment)
    for (int i = tid; i < m; i += 256) eb[i] = (unsigned)sortedS[i];
}

// bf16 helpers
__device__ inline uint pack_bf16(float a, float b) {
    uint ua = __float_as_uint(a), ub = __float_as_uint(b);
    ua = (ua + 0x7fffu + ((ua >> 16) & 1u)) >> 16;           // RNE, low half
    ub = (ub + 0x7fffu + ((ub >> 16) & 1u)) & 0xffff0000u;   // RNE, high half
    return ua | ub;
}
__device__ inline unsigned short bf16r(float f) {
    uint u = __float_as_uint(f);
    return (unsigned short)((u + 0x7fffu + ((u >> 16) & 1u)) >> 16);
}
__device__ inline void acc_bf16x8(float* acc, uint4 v) {
    const uint u[4] = {v.x, v.y, v.z, v.w};
#pragma unroll
    for (int i = 0; i < 4; i++) {
        acc[2 * i]     += __uint_as_float(u[i] << 16);
        acc[2 * i + 1] += __uint_as_float(u[i] & 0xffff0000u);
    }
}

// ---------------- MFMA GEMM: ybf16[r] = (x[r] @ W) * dinv[r] ----------------
// 256 thr = 4 waves; block tile 128 rows x 64 ch; wave w owns rows w*32..+31
// (2 mtiles x 4 ntiles of 16x16, mfma_f32_16x16x32_bf16, K-chunks of 32).
// y rows stored with stride CREAL (64 for layer 1, 40 packed for layer 2);
// row n (sentinel) zeroed by block 0 so aggregation needs no tail masking.

template <int K, int CREAL>
__global__ __launch_bounds__(256) void gemm_mfma_kernel(const float* __restrict__ x,
                                                        const float* __restrict__ W,
                                                        const float* __restrict__ dinv,
                                                        unsigned short* __restrict__ y,
                                                        int n) {
    constexpr int KP = K + 8;                 // wt row stride (bf16); *2B = mult of 16 ✓
    __shared__ unsigned short wt[64 * KP];    // W^T, channels padded to 64 with zeros
    __shared__ unsigned short as[128 * 40];   // A chunk, stride 40 bf16 = 80 B
    const int t = threadIdx.x;
    const int l = t & 63;
    const int w = t >> 6;                     // wave 0..3
    const int lane15 = l & 15;
    const int quad = l >> 4;                  // 0..3
    const int row0 = blockIdx.x * 128;

    // zero the sentinel row n (read by aggregation for ragged tails)
    if (blockIdx.x == 0 && t < CREAL) y[(size_t)n * CREAL + t] = 0;

    // stage Wt (one-time). idx over K*16 float4-chunks of W rows.
    for (int idx = t; idx < K * 16; idx += 256) {
        const int k = idx >> 4;
        const int c4 = (idx & 15) * 4;
        float4 g = make_float4(0.f, 0.f, 0.f, 0.f);
        if (c4 < CREAL) g = *(const float4*)(W + (size_t)k * CREAL + c4);
        wt[(c4 + 0) * KP + k] = bf16r(g.x);
        wt[(c4 + 1) * KP + k] = bf16r(g.y);
        wt[(c4 + 2) * KP + k] = bf16r(g.z);
        wt[(c4 + 3) * KP + k] = bf16r(g.w);
    }

    f32x4 acc[2][4];
#pragma unroll
    for (int mt = 0; mt < 2; mt++)
#pragma unroll
        for (int nt = 0; nt < 4; nt++) acc[mt][nt] = (f32x4){0.f, 0.f, 0.f, 0.f};

    float4 g[4];
    // prefetch chunk 0
#pragma unroll
    for (int p = 0; p < 4; p++) {
        const int idx = t + p * 256;
        const int row = idx >> 3;
        const int kq = idx & 7;
        const int gr = min(row0 + row, n - 1);
        g[p] = *(const float4*)(x + (size_t)gr * K + kq * 4);
    }

    for (int kc = 0; kc < K; kc += 32) {
        __syncthreads();                      // as consumed (and wt staged, first iter)
#pragma unroll
        for (int p = 0; p < 4; p++) {
            const int idx = t + p * 256;
            const int row = idx >> 3;
            const int kq = idx & 7;
            uint2 pk;
            pk.x = pack_bf16(g[p].x, g[p].y);
            pk.y = pack_bf16(g[p].z, g[p].w);
            *(uint2*)(as + row * 40 + kq * 4) = pk;
        }
        if (kc + 32 < K) {                    // prefetch next chunk (in flight over mfma)
#pragma unroll
            for (int p = 0; p < 4; p++) {
                const int idx = t + p * 256;
                const int row = idx >> 3;
                const int kq = idx & 7;
                const int gr = min(row0 + row, n - 1);
                g[p] = *(const float4*)(x + (size_t)gr * K + kc + 32 + kq * 4);
            }
        }
        __syncthreads();

        short8 bf[4];
#pragma unroll
        for (int nt = 0; nt < 4; nt++)
            bf[nt] = *(const short8*)(wt + (nt * 16 + lane15) * KP + kc + quad * 8);
#pragma unroll
        for (int mt = 0; mt < 2; mt++) {
            const short8 af =
                *(const short8*)(as + (w * 32 + mt * 16 + lane15) * 40 + quad * 8);
#pragma unroll
            for (int nt = 0; nt < 4; nt++)
                acc[mt][nt] =
                    __builtin_amdgcn_mfma_f32_16x16x32_bf16(af, bf[nt], acc[mt][nt], 0, 0, 0);
        }
    }

    // epilogue: D[row=quad*4+r][col=lane15] per tile; scale by dinv, store bf16
#pragma unroll
    for (int mt = 0; mt < 2; mt++) {
#pragma unroll
        for (int r = 0; r < 4; r++) {
            const int row = row0 + w * 32 + mt * 16 + quad * 4 + r;
            if (row < n) {
                const float di = dinv[row];
#pragma unroll
                for (int nt = 0; nt < 4; nt++) {
                    const int col = nt * 16 + lane15;
                    if (col < CREAL)
                        y[(size_t)row * CREAL + col] = bf16r(acc[mt][nt][r] * di);
                }
            }
        }
    }
}

// ---------------- Aggregation, C=64 bf16 (+bias, ReLU), h1 out fp32 ----------------
// sentinel row n (all zero) lets ragged tails run unmasked: default shuffle idx = n.

__global__ __launch_bounds__(256) void agg64_kernel(const unsigned short* __restrict__ y,
                                                    const int* __restrict__ row_off,
                                                    const int* __restrict__ deg,
                                                    const unsigned* __restrict__ nbr,
                                                    const float* __restrict__ dinv,
                                                    const float* __restrict__ b,
                                                    float* __restrict__ out, int n) {
    int node = blockIdx.x * 4 + (threadIdx.x >> 6);
    if (node >= n) return;
    const int l = threadIdx.x & 63;
    const int g = l >> 3;            // 0..7
    const int cq = l & 7;            // 16B chunk within row; channels cq*8..cq*8+7

    const int start = row_off[node];
    const int dg = deg[node];

    float acc[8];
#pragma unroll
    for (int i = 0; i < 8; i++) acc[i] = 0.f;

    for (int base = 0; base < dg; base += 64) {
        const int m = min(64, dg - base);
        const int idx = (l < m) ? (int)nbr[start + base + l] : n;   // sentinel: zero row
        for (int j0 = 0; j0 < m; j0 += 16) {
            const int sA = __shfl(idx, j0 + g);
            const int sB = __shfl(idx, j0 + 8 + g);
            const uint4 vA = ((const uint4*)(y + (size_t)sA * 64))[cq];
            const uint4 vB = ((const uint4*)(y + (size_t)sB * 64))[cq];
            acc_bf16x8(acc, vA);
            acc_bf16x8(acc, vB);
        }
    }
    // reduce across the 8 groups
#pragma unroll
    for (int off = 8; off < 64; off <<= 1)
#pragma unroll
        for (int i = 0; i < 8; i++) acc[i] += __shfl_xor(acc[i], off);

    // self-loop + scale + bias + relu; lanes 0..7 write fp32 h1
    float self[8];
#pragma unroll
    for (int i = 0; i < 8; i++) self[i] = 0.f;
    acc_bf16x8(self, ((const uint4*)(y + (size_t)node * 64))[cq]);
    const float di = dinv[node];
    const float4 bv0 = *(const float4*)(b + cq * 8);
    const float4 bv1 = *(const float4*)(b + cq * 8 + 4);
    const float bb[8] = {bv0.x, bv0.y, bv0.z, bv0.w, bv1.x, bv1.y, bv1.z, bv1.w};
    if (l < 8) {
        float4 o0, o1;
        o0.x = fmaxf((acc[0] + self[0]) * di + bb[0], 0.f);
        o0.y = fmaxf((acc[1] + self[1]) * di + bb[1], 0.f);
        o0.z = fmaxf((acc[2] + self[2]) * di + bb[2], 0.f);
        o0.w = fmaxf((acc[3] + self[3]) * di + bb[3], 0.f);
        o1.x = fmaxf((acc[4] + self[4]) * di + bb[4], 0.f);
        o1.y = fmaxf((acc[5] + self[5]) * di + bb[5], 0.f);
        o1.z = fmaxf((acc[6] + self[6]) * di + bb[6], 0.f);
        o1.w = fmaxf((acc[7] + self[7]) * di + bb[7], 0.f);
        *(float4*)(out + (size_t)node * 64 + l * 8) = o0;
        *(float4*)(out + (size_t)node * 64 + l * 8 + 4) = o1;
    }
}

// ---------------- Aggregation C=40 packed (80B rows) + log_softmax ----------------
// lane = cq*12 + g: 5 chunks (uint4 = 8 ch) x 12 neighbor groups (lanes 60-63 spare).
// Sentinel row n removes all tail masking. 12-way reduce: predicated shfl_down tree.

__global__ __launch_bounds__(256) void agg40_lsm_kernel(const unsigned short* __restrict__ y,
                                                        const int* __restrict__ row_off,
                                                        const int* __restrict__ deg,
                                                        const unsigned* __restrict__ nbr,
                                                        const float* __restrict__ dinv,
                                                        const float* __restrict__ b,
                                                        float* __restrict__ out, int n) {
    int node = blockIdx.x * 4 + (threadIdx.x >> 6);
    if (node >= n) return;
    const int l = threadIdx.x & 63;
    const int cq0 = l / 12;                 // 0..5
    const int g = l - cq0 * 12;             // 0..11
    const int cq = min(cq0, 4);             // lanes 60-63 mirror chunk 4 (same addrs, free)
    const bool lead = (g == 0) && (cq0 < 5);  // lanes 0,12,24,36,48

    const int start = row_off[node];
    const int dg = deg[node];

    float acc[8];
#pragma unroll
    for (int i = 0; i < 8; i++) acc[i] = 0.f;

    for (int base = 0; base < dg; base += 60) {
        const int m = min(60, dg - base);
        const int idx = (l < m) ? (int)nbr[start + base + l] : n;   // sentinel: zero row
        for (int r = 0; r * 12 < m; ++r) {
            const int s = __shfl(idx, r * 12 + g);
            const uint4 v = *((const uint4*)(y + (size_t)s * 40) + cq);
            acc_bf16x8(acc, v);
        }
    }

    // reduce 12 groups within each contiguous 12-lane segment
#pragma unroll
    for (int i = 0; i < 8; i++) { const float t = __shfl_down(acc[i], 8); if (g < 4) acc[i] += t; }
#pragma unroll
    for (int i = 0; i < 8; i++) { const float t = __shfl_down(acc[i], 4); if (g < 4) acc[i] += t; }
#pragma unroll
    for (int i = 0; i < 8; i++) { const float t = __shfl_down(acc[i], 2); if (g < 2) acc[i] += t; }
#pragma unroll
    for (int i = 0; i < 8; i++) { const float t = __shfl_down(acc[i], 1); if (g == 0) acc[i] += t; }

    // self-loop on lead lanes only
    if (lead) {
        const uint4 v = *((const uint4*)(y + (size_t)node * 40) + cq);
        acc_bf16x8(acc, v);
    }

    const float di = dinv[node];
    const float4 bv0 = *(const float4*)(b + cq * 8);
    const float4 bv1 = *(const float4*)(b + cq * 8 + 4);
    const float bb[8] = {bv0.x, bv0.y, bv0.z, bv0.w, bv1.x, bv1.y, bv1.z, bv1.w};
    float h[8];
#pragma unroll
    for (int i = 0; i < 8; i++) h[i] = acc[i] * di + bb[i];

    // log_softmax over 40 values held by the 5 lead lanes (8 each)
    float mx = -INFINITY;
#pragma unroll
    for (int i = 0; i < 8; i++) mx = fmaxf(mx, h[i]);
    {
        const float m0 = __shfl(mx, 0), m1 = __shfl(mx, 12), m2 = __shfl(mx, 24),
                    m3 = __shfl(mx, 36), m4 = __shfl(mx, 48);
        mx = fmaxf(fmaxf(fmaxf(m0, m1), fmaxf(m2, m3)), m4);
    }
    float es = 0.f;
#pragma unroll
    for (int i = 0; i < 8; i++) es += __expf(h[i] - mx);
    {
        const float e0 = __shfl(es, 0), e1 = __shfl(es, 12), e2 = __shfl(es, 24),
                    e3 = __shfl(es, 36), e4 = __shfl(es, 48);
        es = ((e0 + e1) + (e2 + e3)) + e4;
    }
    const float ls = mx + __logf(es);

    if (lead) {   // lanes 0,12,24,36,48 write chunks 0..4 (32B each, contiguous row)
        float4 o0, o1;
        o0.x = h[0] - ls; o0.y = h[1] - ls; o0.z = h[2] - ls; o0.w = h[3] - ls;
        o1.x = h[4] - ls; o1.y = h[5] - ls; o1.z = h[6] - ls; o1.w = h[7] - ls;
        *(float4*)(out + (size_t)node * 40 + cq * 8) = o0;
        *(float4*)(out + (size_t)node * 40 + cq * 8 + 4) = o1;
    }
}

// ---------------- launch ----------------

extern "C" void kernel_launch(void* const* d_in, const int* in_sizes, int n_in,
                              void* d_out, int out_size, void* d_ws, size_t ws_size,
                              hipStream_t stream) {
    const float* x  = (const float*)d_in[0];
    const int* edges = (const int*)d_in[1];
    const float* W1 = (const float*)d_in[2];
    const float* b1 = (const float*)d_in[3];
    const float* W2 = (const float*)d_in[4];
    const float* b2 = (const float*)d_in[5];
    float* out = (float*)d_out;

    const int n = NN;
    const int E = in_sizes[1] / 2;

    char* ws = (char*)d_ws;
    size_t off = 0;
    auto alloc = [&](size_t bytes) -> void* {
        void* p = ws + off;
        off += (bytes + 255) & ~(size_t)255;
        return p;
    };
    int*            bcur    = (int*)alloc((size_t)NB * 4);
    unsigned*       bkt     = (unsigned*)alloc((size_t)NB * BCAP * 4);  // becomes nbr
    int*            row_off = (int*)alloc((size_t)n * 4);
    int*            deg     = (int*)alloc((size_t)n * 4);
    float*          dinv    = (float*)alloc((size_t)n * 4);
    float*          h1      = (float*)alloc((size_t)n * 64 * 4);
    unsigned short* y1      = (unsigned short*)alloc((size_t)(n + 1) * 64 * 2);  // bf16 + sentinel
    unsigned short* y2      = y1;   // y1 dead after agg64; reuse for layer-2 xw (stride 40)

    const int* src = edges;
    const int* dst = edges + E;

    hipMemsetAsync(bcur, 0, (size_t)NB * 4, stream);
    partition_kernel<<<NBLK_PART, 256, 0, stream>>>(src, dst, bcur, bkt, E);
    bucket_sort_kernel<<<NB, 256, 0, stream>>>(bcur, bkt, row_off, deg, dinv, n);

    const int gblk = (n + 127) / 128;   // 782

    // layer 1: y1 = bf16((x @ W1) * dinv) ; h1 = relu(agg(y1) * dinv + b1)
    gemm_mfma_kernel<256, 64><<<gblk, 256, 0, stream>>>(x, W1, dinv, y1, n);
    agg64_kernel<<<(n + 3) / 4, 256, 0, stream>>>(y1, row_off, deg, bkt, dinv, b1, h1, n);

    // layer 2: y2 = bf16((h1 @ W2) * dinv) packed to 40 ch ; out = log_softmax(agg + b2)
    gemm_mfma_kernel<64, 40><<<gblk, 256, 0, stream>>>(h1, W2, dinv, y2, n);
    agg40_lsm_kernel<<<(n + 3) / 4, 256, 0, stream>>>(y2, row_off, deg, bkt, dinv, b2, out, n);
}

// Round 2
// 370.929 us; speedup vs baseline: 1.0005x; 1.0005x over previous
//
#include <hip/hip_runtime.h>
#include <math.h>

#define NN 100000
#define NB 256        // coarse buckets
#define RANGE 392     // nodes per bucket (256*392 = 100352 >= 100000)
#define CAP 56        // staging entries per bucket per block
#define BCAP 13824    // bucket capacity (mean 12544, sigma ~112 -> 11 sigma)
#define NBLK_PART 512

typedef unsigned int uint;
typedef __attribute__((ext_vector_type(8))) short short8;
typedef __attribute__((ext_vector_type(4))) float f32x4;
typedef __attribute__((ext_vector_type(2))) float f32x2;

// ---------------- partition: edges -> 256 dst-range buckets ----------------

__global__ __launch_bounds__(256) void partition_kernel(const int* __restrict__ src,
                                                        const int* __restrict__ dst,
                                                        int* __restrict__ bcur,
                                                        unsigned* __restrict__ bkt, int E) {
    __shared__ unsigned stage[NB * CAP];
    __shared__ int lcnt[NB];
    __shared__ int baseS[NB];
    for (int i = threadIdx.x; i < NB; i += 256) lcnt[i] = 0;
    __syncthreads();

    const int nq = E >> 2;
    const int stride = gridDim.x * blockDim.x;
    for (int q = blockIdx.x * blockDim.x + threadIdx.x; q < nq; q += stride) {
        const int4 s4 = ((const int4*)src)[q];
        const int4 d4 = ((const int4*)dst)[q];
#pragma unroll
        for (int k = 0; k < 4; k++) {
            const int s = (&s4.x)[k];
            const int d = (&d4.x)[k];
            const unsigned b = (unsigned)d / RANGE;
            const unsigned ent = ((unsigned)s << 9) | ((unsigned)d - b * RANGE);
            const int slot = atomicAdd(&lcnt[b], 1);
            if (slot < CAP) {
                stage[b * CAP + slot] = ent;
            } else {                       // rare overflow: direct global path
                const int pos = atomicAdd(&bcur[b], 1);
                if (pos < BCAP) bkt[(size_t)b * BCAP + pos] = ent;
            }
        }
    }
    // tail edges (E % 4)
    const int gid = blockIdx.x * blockDim.x + threadIdx.x;
    if (gid < (E & 3)) {
        const int e = (E & ~3) + gid;
        const int s = src[e], d = dst[e];
        const unsigned b = (unsigned)d / RANGE;
        const unsigned ent = ((unsigned)s << 9) | ((unsigned)d - b * RANGE);
        const int pos = atomicAdd(&bcur[b], 1);
        if (pos < BCAP) bkt[(size_t)b * BCAP + pos] = ent;
    }
    __syncthreads();

    // reserve all bucket bases in parallel (one atomic per bucket)
    if (threadIdx.x < NB) {
        const int c = min(lcnt[threadIdx.x], CAP);
        baseS[threadIdx.x] = (c > 0) ? atomicAdd(&bcur[threadIdx.x], c) : 0;
    }
    __syncthreads();

    // flush: contiguous chunk write per bucket
    const int w = threadIdx.x >> 6, l = threadIdx.x & 63;
    for (int b = w; b < NB; b += 4) {
        const int cnt = min(lcnt[b], CAP);
        const int base = baseS[b];
        for (int i = l; i < cnt; i += 64) {
            const int pos = base + i;
            if (pos < BCAP) bkt[(size_t)b * BCAP + pos] = stage[b * CAP + i];
        }
    }
}

// ---------------- per-bucket counting sort -> CSR (+deg/dinv) ----------------

__global__ __launch_bounds__(256) void bucket_sort_kernel(const int* __restrict__ bcur,
                                                          unsigned* __restrict__ bkt,
                                                          int* __restrict__ row_off,
                                                          int* __restrict__ deg,
                                                          float* __restrict__ dinv, int n) {
    __shared__ int sortedS[BCAP];
    __shared__ int cntS[RANGE];
    __shared__ int offS[RANGE];
    const int b = blockIdx.x;
    const int tid = threadIdx.x;
    unsigned* eb = bkt + (size_t)b * BCAP;
    const int m = min(bcur[b], BCAP);

    for (int i = tid; i < RANGE; i += 256) cntS[i] = 0;
    __syncthreads();
    for (int i = tid; i < m; i += 256) atomicAdd(&cntS[(int)(eb[i] & 511u)], 1);
    __syncthreads();

    // exclusive scan of cntS[0..RANGE) by wave 0
    if (tid < 64) {
        const int l = tid;
        int carry = 0;
        for (int base = 0; base < RANGE; base += 64) {
            const int i = base + l;
            const int c = (i < RANGE) ? cntS[i] : 0;
            int v = c;
#pragma unroll
            for (int off = 1; off < 64; off <<= 1) {
                const int t2 = __shfl_up(v, off);
                if (l >= off) v += t2;
            }
            if (i < RANGE) offS[i] = carry + v - c;
            carry += __shfl(v, 63);
        }
    }
    __syncthreads();

    // emit CSR metadata
    for (int i = tid; i < RANGE; i += 256) {
        const int node = b * RANGE + i;
        if (node < n) {
            row_off[node] = b * BCAP + offS[i];
            deg[node] = cntS[i];
            dinv[node] = rsqrtf((float)cntS[i] + 1.0f);   // +1 self-loop
        }
    }
    __syncthreads();

    // scatter into LDS (offS doubles as cursor now)
    for (int i = tid; i < m; i += 256) {
        const unsigned e = eb[i];
        const int pos = atomicAdd(&offS[(int)(e & 511u)], 1);
        sortedS[pos] = (int)(e >> 9);
    }
    __syncthreads();

    // in-place contiguous write-back (bkt segment becomes the nbr segment)
    for (int i = tid; i < m; i += 256) eb[i] = (unsigned)sortedS[i];
}

// bf16 helpers
__device__ inline uint pack_bf16(float a, float b) {
    uint ua = __float_as_uint(a), ub = __float_as_uint(b);
    ua = (ua + 0x7fffu + ((ua >> 16) & 1u)) >> 16;           // RNE, low half
    ub = (ub + 0x7fffu + ((ub >> 16) & 1u)) & 0xffff0000u;   // RNE, high half
    return ua | ub;
}
__device__ inline unsigned short bf16r(float f) {
    uint u = __float_as_uint(f);
    return (unsigned short)((u + 0x7fffu + ((u >> 16) & 1u)) >> 16);
}
// unpack 2 bf16 -> f32x2 and packed-add (v_pk_add_f32 on CDNA4)
__device__ inline void acc_bf16x8p(f32x2* acc, uint4 v) {
    const uint u[4] = {v.x, v.y, v.z, v.w};
#pragma unroll
    for (int i = 0; i < 4; i++) {
        f32x2 t;
        t.x = __uint_as_float(u[i] << 16);
        t.y = __uint_as_float(u[i] & 0xffff0000u);
        acc[i] += t;
    }
}

// ---------------- MFMA GEMM: ybf16[r] = (x[r] @ W) * dinv[r], 64 ch padded ----------------
// 256 thr = 4 waves; block tile 128 rows x 64 ch; wave w owns rows w*32..+31
// (2 mtiles x 4 ntiles of 16x16, mfma_f32_16x16x32_bf16, K-chunks of 32).
// y stride 64 (128-B aligned rows; padding channels are exact zeros since W is
// zero-padded). Row n (sentinel) zeroed so aggregation needs no tail masking.

template <int K, int CREAL>
__global__ __launch_bounds__(256) void gemm_mfma_kernel(const float* __restrict__ x,
                                                        const float* __restrict__ W,
                                                        const float* __restrict__ dinv,
                                                        unsigned short* __restrict__ y,
                                                        int n) {
    constexpr int KP = K + 8;                 // wt row stride (bf16); *2B = mult of 16 ✓
    __shared__ unsigned short wt[64 * KP];    // W^T, channels padded to 64 with zeros
    __shared__ unsigned short as[128 * 40];   // A chunk, stride 40 bf16 = 80 B
    const int t = threadIdx.x;
    const int l = t & 63;
    const int w = t >> 6;                     // wave 0..3
    const int lane15 = l & 15;
    const int quad = l >> 4;                  // 0..3
    const int row0 = blockIdx.x * 128;

    // zero the sentinel row n (read by aggregation for ragged tails)
    if (blockIdx.x == 0 && t < 64) y[(size_t)n * 64 + t] = 0;

    // stage Wt (one-time). idx over K*16 float4-chunks of W rows.
    for (int idx = t; idx < K * 16; idx += 256) {
        const int k = idx >> 4;
        const int c4 = (idx & 15) * 4;
        float4 g = make_float4(0.f, 0.f, 0.f, 0.f);
        if (c4 < CREAL) g = *(const float4*)(W + (size_t)k * CREAL + c4);
        wt[(c4 + 0) * KP + k] = bf16r(g.x);
        wt[(c4 + 1) * KP + k] = bf16r(g.y);
        wt[(c4 + 2) * KP + k] = bf16r(g.z);
        wt[(c4 + 3) * KP + k] = bf16r(g.w);
    }

    f32x4 acc[2][4];
#pragma unroll
    for (int mt = 0; mt < 2; mt++)
#pragma unroll
        for (int nt = 0; nt < 4; nt++) acc[mt][nt] = (f32x4){0.f, 0.f, 0.f, 0.f};

    float4 g[4];
    // prefetch chunk 0
#pragma unroll
    for (int p = 0; p < 4; p++) {
        const int idx = t + p * 256;
        const int row = idx >> 3;
        const int kq = idx & 7;
        const int gr = min(row0 + row, n - 1);
        g[p] = *(const float4*)(x + (size_t)gr * K + kq * 4);
    }

    for (int kc = 0; kc < K; kc += 32) {
        __syncthreads();                      // as consumed (and wt staged, first iter)
#pragma unroll
        for (int p = 0; p < 4; p++) {
            const int idx = t + p * 256;
            const int row = idx >> 3;
            const int kq = idx & 7;
            uint2 pk;
            pk.x = pack_bf16(g[p].x, g[p].y);
            pk.y = pack_bf16(g[p].z, g[p].w);
            *(uint2*)(as + row * 40 + kq * 4) = pk;
        }
        if (kc + 32 < K) {                    // prefetch next chunk (in flight over mfma)
#pragma unroll
            for (int p = 0; p < 4; p++) {
                const int idx = t + p * 256;
                const int row = idx >> 3;
                const int kq = idx & 7;
                const int gr = min(row0 + row, n - 1);
                g[p] = *(const float4*)(x + (size_t)gr * K + kc + 32 + kq * 4);
            }
        }
        __syncthreads();

        short8 bf[4];
#pragma unroll
        for (int nt = 0; nt < 4; nt++)
            bf[nt] = *(const short8*)(wt + (nt * 16 + lane15) * KP + kc + quad * 8);
#pragma unroll
        for (int mt = 0; mt < 2; mt++) {
            const short8 af =
                *(const short8*)(as + (w * 32 + mt * 16 + lane15) * 40 + quad * 8);
#pragma unroll
            for (int nt = 0; nt < 4; nt++)
                acc[mt][nt] =
                    __builtin_amdgcn_mfma_f32_16x16x32_bf16(af, bf[nt], acc[mt][nt], 0, 0, 0);
        }
    }

    // epilogue: D[row=quad*4+r][col=lane15] per tile; scale by dinv, store bf16
#pragma unroll
    for (int mt = 0; mt < 2; mt++) {
#pragma unroll
        for (int r = 0; r < 4; r++) {
            const int row = row0 + w * 32 + mt * 16 + quad * 4 + r;
            if (row < n) {
                const float di = dinv[row];
#pragma unroll
                for (int nt = 0; nt < 4; nt++)
                    y[(size_t)row * 64 + nt * 16 + lane15] = bf16r(acc[mt][nt][r] * di);
            }
        }
    }
}

// ---------------- Aggregation, C=64 bf16 (+bias, ReLU), h1 out fp32 ----------------
// sentinel row n (all zero) lets ragged tails run unmasked: default shuffle idx = n.
// lane = g*8 + cq: 8 neighbor groups x 8 chunks; each group reads one full
// 128-B aligned row (perfectly coalesced).

__global__ __launch_bounds__(256) void agg64_kernel(const unsigned short* __restrict__ y,
                                                    const int* __restrict__ row_off,
                                                    const int* __restrict__ deg,
                                                    const unsigned* __restrict__ nbr,
                                                    const float* __restrict__ dinv,
                                                    const float* __restrict__ b,
                                                    float* __restrict__ out, int n) {
    int node = blockIdx.x * 4 + (threadIdx.x >> 6);
    if (node >= n) return;
    const int l = threadIdx.x & 63;
    const int g = l >> 3;            // 0..7
    const int cq = l & 7;            // 16B chunk within row; channels cq*8..cq*8+7

    const int start = row_off[node];
    const int dg = deg[node];

    f32x2 acc[4];
#pragma unroll
    for (int i = 0; i < 4; i++) acc[i] = (f32x2){0.f, 0.f};

    for (int base = 0; base < dg; base += 64) {
        const int m = min(64, dg - base);
        const int idx = (l < m) ? (int)nbr[start + base + l] : n;   // sentinel: zero row
        for (int j0 = 0; j0 < m; j0 += 16) {
            const int sA = __shfl(idx, j0 + g);
            const int sB = __shfl(idx, j0 + 8 + g);
            const uint4 vA = ((const uint4*)(y + (size_t)sA * 64))[cq];
            const uint4 vB = ((const uint4*)(y + (size_t)sB * 64))[cq];
            acc_bf16x8p(acc, vA);
            acc_bf16x8p(acc, vB);
        }
    }
    // reduce across the 8 groups
    float* af = (float*)acc;
#pragma unroll
    for (int off = 8; off < 64; off <<= 1)
#pragma unroll
        for (int i = 0; i < 8; i++) af[i] += __shfl_xor(af[i], off);

    // self-loop + scale + bias + relu; lanes 0..7 write fp32 h1
    f32x2 self[4];
#pragma unroll
    for (int i = 0; i < 4; i++) self[i] = (f32x2){0.f, 0.f};
    acc_bf16x8p(self, ((const uint4*)(y + (size_t)node * 64))[cq]);
    const float* sf = (const float*)self;
    const float di = dinv[node];
    const float4 bv0 = *(const float4*)(b + cq * 8);
    const float4 bv1 = *(const float4*)(b + cq * 8 + 4);
    const float bb[8] = {bv0.x, bv0.y, bv0.z, bv0.w, bv1.x, bv1.y, bv1.z, bv1.w};
    if (l < 8) {
        float4 o0, o1;
        o0.x = fmaxf((af[0] + sf[0]) * di + bb[0], 0.f);
        o0.y = fmaxf((af[1] + sf[1]) * di + bb[1], 0.f);
        o0.z = fmaxf((af[2] + sf[2]) * di + bb[2], 0.f);
        o0.w = fmaxf((af[3] + sf[3]) * di + bb[3], 0.f);
        o1.x = fmaxf((af[4] + sf[4]) * di + bb[4], 0.f);
        o1.y = fmaxf((af[5] + sf[5]) * di + bb[5], 0.f);
        o1.z = fmaxf((af[6] + sf[6]) * di + bb[6], 0.f);
        o1.w = fmaxf((af[7] + sf[7]) * di + bb[7], 0.f);
        *(float4*)(out + (size_t)node * 64 + l * 8) = o0;
        *(float4*)(out + (size_t)node * 64 + l * 8 + 4) = o1;
    }
}

// ---------------- Aggregation C=40 (rows stride 64, padded) + log_softmax ----------------
// lane = g*5 + cq: 12 neighbor groups x 5 chunks. Each group of 5 CONSECUTIVE
// lanes reads 80 contiguous bytes of one 128-B-aligned row (1 line, coalesced);
// the 3 padding chunks are never loaded/accumulated. Lanes 60-63 duplicate
// group 11 (broadcast loads, results unused). Sentinel row n removes masking.

__global__ __launch_bounds__(256) void agg40_lsm_kernel(const unsigned short* __restrict__ y,
                                                        const int* __restrict__ row_off,
                                                        const int* __restrict__ deg,
                                                        const unsigned* __restrict__ nbr,
                                                        const float* __restrict__ dinv,
                                                        const float* __restrict__ b,
                                                        float* __restrict__ out, int n) {
    int node = blockIdx.x * 4 + (threadIdx.x >> 6);
    if (node >= n) return;
    const int l = threadIdx.x & 63;
    int gg = l / 5;
    int cq = l - gg * 5;             // 0..4, chunk (channels cq*8..cq*8+7)
    if (l >= 60) { gg = 11; cq = l - 60; }   // dup of group 11, lanes 55+cq

    const int start = row_off[node];
    const int dg = deg[node];

    f32x2 acc[4];
#pragma unroll
    for (int i = 0; i < 4; i++) acc[i] = (f32x2){0.f, 0.f};

    for (int base = 0; base < dg; base += 60) {
        const int m = min(60, dg - base);
        const int idx = (l < m) ? (int)nbr[start + base + l] : n;   // sentinel: zero row
        for (int r = 0; r * 12 < m; ++r) {
            const int s = __shfl(idx, r * 12 + gg);
            const uint4 v = *((const uint4*)(y + (size_t)s * 64) + cq);
            acc_bf16x8p(acc, v);
        }
    }

    // reduce the 12 groups (stride-5 lanes share a chunk): tree on g.
    // step1: g<6 += g+6 (lane+30); step2: g<3 += g+3 (lane+15);
    // step3: g==0 += g1 (lane+5) and g2 (lane+10). sources never modified early.
    float* af = (float*)acc;
#pragma unroll
    for (int i = 0; i < 8; i++) { const float t = __shfl_down(af[i], 30); if (l < 30) af[i] += t; }
#pragma unroll
    for (int i = 0; i < 8; i++) { const float t = __shfl_down(af[i], 15); if (l < 15) af[i] += t; }
#pragma unroll
    for (int i = 0; i < 8; i++) { const float t = __shfl_down(af[i], 5);  if (l < 5)  af[i] += t; }
#pragma unroll
    for (int i = 0; i < 8; i++) { const float t = __shfl_down(af[i], 10); if (l < 5)  af[i] += t; }

    // self-loop on lanes 0..4 (g=0, cq=l)
    if (l < 5) {
        const uint4 v = *((const uint4*)(y + (size_t)node * 64) + cq);
        acc_bf16x8p(acc, v);
    }

    const float di = dinv[node];
    const float4 bv0 = *(const float4*)(b + cq * 8);
    const float4 bv1 = *(const float4*)(b + cq * 8 + 4);
    const float bb[8] = {bv0.x, bv0.y, bv0.z, bv0.w, bv1.x, bv1.y, bv1.z, bv1.w};
    float h[8];
#pragma unroll
    for (int i = 0; i < 8; i++) h[i] = af[i] * di + bb[i];

    // log_softmax over 40 values held by lanes 0..4 (8 each)
    float mx = -INFINITY;
#pragma unroll
    for (int i = 0; i < 8; i++) mx = fmaxf(mx, h[i]);
    {
        const float m0 = __shfl(mx, 0), m1 = __shfl(mx, 1), m2 = __shfl(mx, 2),
                    m3 = __shfl(mx, 3), m4 = __shfl(mx, 4);
        mx = fmaxf(fmaxf(fmaxf(m0, m1), fmaxf(m2, m3)), m4);
    }
    float es = 0.f;
#pragma unroll
    for (int i = 0; i < 8; i++) es += __expf(h[i] - mx);
    {
        const float e0 = __shfl(es, 0), e1 = __shfl(es, 1), e2 = __shfl(es, 2),
                    e3 = __shfl(es, 3), e4 = __shfl(es, 4);
        es = ((e0 + e1) + (e2 + e3)) + e4;
    }
    const float ls = mx + __logf(es);

    if (l < 5) {   // lanes 0..4 write chunks 0..4 (32 B each, contiguous 160-B row)
        float4 o0, o1;
        o0.x = h[0] - ls; o0.y = h[1] - ls; o0.z = h[2] - ls; o0.w = h[3] - ls;
        o1.x = h[4] - ls; o1.y = h[5] - ls; o1.z = h[6] - ls; o1.w = h[7] - ls;
        *(float4*)(out + (size_t)node * 40 + cq * 8) = o0;
        *(float4*)(out + (size_t)node * 40 + cq * 8 + 4) = o1;
    }
}

// ---------------- launch ----------------

extern "C" void kernel_launch(void* const* d_in, const int* in_sizes, int n_in,
                              void* d_out, int out_size, void* d_ws, size_t ws_size,
                              hipStream_t stream) {
    const float* x  = (const float*)d_in[0];
    const int* edges = (const int*)d_in[1];
    const float* W1 = (const float*)d_in[2];
    const float* b1 = (const float*)d_in[3];
    const float* W2 = (const float*)d_in[4];
    const float* b2 = (const float*)d_in[5];
    float* out = (float*)d_out;

    const int n = NN;
    const int E = in_sizes[1] / 2;

    char* ws = (char*)d_ws;
    size_t off = 0;
    auto alloc = [&](size_t bytes) -> void* {
        void* p = ws + off;
        off += (bytes + 255) & ~(size_t)255;
        return p;
    };
    int*            bcur    = (int*)alloc((size_t)NB * 4);
    unsigned*       bkt     = (unsigned*)alloc((size_t)NB * BCAP * 4);  // becomes nbr
    int*            row_off = (int*)alloc((size_t)n * 4);
    int*            deg     = (int*)alloc((size_t)n * 4);
    float*          dinv    = (float*)alloc((size_t)n * 4);
    float*          h1      = (float*)alloc((size_t)n * 64 * 4);
    unsigned short* y1      = (unsigned short*)alloc((size_t)(n + 1) * 64 * 2);  // bf16 + sentinel
    unsigned short* y2      = y1;   // y1 dead after agg64; reuse for layer-2 xw

    const int* src = edges;
    const int* dst = edges + E;

    hipMemsetAsync(bcur, 0, (size_t)NB * 4, stream);
    partition_kernel<<<NBLK_PART, 256, 0, stream>>>(src, dst, bcur, bkt, E);
    bucket_sort_kernel<<<NB, 256, 0, stream>>>(bcur, bkt, row_off, deg, dinv, n);

    const int gblk = (n + 127) / 128;   // 782

    // layer 1: y1 = bf16((x @ W1) * dinv) ; h1 = relu(agg(y1) * dinv + b1)
    gemm_mfma_kernel<256, 64><<<gblk, 256, 0, stream>>>(x, W1, dinv, y1, n);
    agg64_kernel<<<(n + 3) / 4, 256, 0, stream>>>(y1, row_off, deg, bkt, dinv, b1, h1, n);

    // layer 2: y2 = bf16((h1 @ W2) * dinv) ; out = log_softmax(agg(y2) * dinv + b2)
    gemm_mfma_kernel<64, 40><<<gblk, 256, 0, stream>>>(h1, W2, dinv, y2, n);
    agg40_lsm_kernel<<<(n + 3) / 4, 256, 0, stream>>>(y2, row_off, deg, bkt, dinv, b2, out, n);
}